// Round 17
// baseline (234.444 us; speedup 1.0000x reference)
//
#include <hip/hip_runtime.h>
#include <hip/hip_bf16.h>

// MHA fwd: B=4, S=1024, H=1024, NH=16, HD=64. fp32 in/out, bf16 MFMA inside.
// d_out = [out 4096x1024 f32] ++ [probs 64x1024x1024 f32]
// d_ws (64MB): qhi 8M | qlo 8M | khi 8M | klo 8M | vt 8M | ctxb 8M | hsb 8M | Wcat 8M
//
// ROUND-16: r15 (208.0us, spill fixed) + coalesced probs epilogue (clean retest of
// r13's idea, which was confounded by the acc-spill). All loops over acc indices
// MUST stay fully unrolled (rule #20: runtime index => scratch spill => 2-3x).

typedef __attribute__((ext_vector_type(8))) short short8;
typedef __attribute__((ext_vector_type(4))) float f32x4;
typedef __attribute__((ext_vector_type(4))) short short4v;

#define LOG2E 1.44269504f
#define MFMA_BF16(a, b, c) __builtin_amdgcn_mfma_f32_16x16x32_bf16((a), (b), (c), 0, 0, 0)

__device__ __forceinline__ short f2bf(float x) {
    __hip_bfloat16 h = __float2bfloat16(x);
    return __builtin_bit_cast(short, h);
}
__device__ __forceinline__ float bf2f(short s) {
    unsigned int u = ((unsigned int)(unsigned short)s) << 16;
    return __builtin_bit_cast(float, u);
}

__device__ __forceinline__ void gload16(const void* g, void* lds) {
    __builtin_amdgcn_global_load_lds(
        (const __attribute__((address_space(1))) void*)g,
        (__attribute__((address_space(3))) void*)lds, 16, 0, 0);
}

// ---------------- fp32 -> bf16 convert, merged: hs (blocks 0..2047) + 4 weights ----------
__global__ __launch_bounds__(256) void cvt_all_kernel(
    const float* __restrict__ hs, short* __restrict__ hsb,
    const float* __restrict__ w0, const float* __restrict__ w1,
    const float* __restrict__ w2, const float* __restrict__ w3,
    short* __restrict__ wcat)
{
    int blk = blockIdx.x;
    const float* src;
    short* dst;
    int li;
    if (blk < 2048) {                       // hidden_states: 4M floats
        src = hs; dst = hsb;
        li = blk * 256 + threadIdx.x;
    } else {                                // weights: 1M floats each
        int sel = (blk - 2048) >> 9;
        const float* srcs[4] = {w0, w1, w2, w3};
        src = srcs[sel];
        dst = wcat + (size_t)sel * 1048576;
        li = ((blk - 2048) & 511) * 256 + threadIdx.x;
    }
    const float4* sp = (const float4*)src;
    float4 a = sp[li * 2], b = sp[li * 2 + 1];
    short8 o;
    o[0] = f2bf(a.x); o[1] = f2bf(a.y); o[2] = f2bf(a.z); o[3] = f2bf(a.w);
    o[4] = f2bf(b.x); o[5] = f2bf(b.y); o[6] = f2bf(b.z); o[7] = f2bf(b.w);
    *(short8*)(dst + (size_t)li * 8) = o;
}

// ---------------- 128x128-tile double-buffered NT GEMM, K=1024 ----------------
// EPI 0: Cf = A@B^T + bias (f32 row-major)
// EPI 1: QKV: n0<1024 -> Q hi/lo (*0.125); <2048 -> K hi/lo; else V->vt. LDS-bounce stores.
template <int EPI>
__global__ __launch_bounds__(256) void gemm128_kernel(
    const short* __restrict__ A, const short* __restrict__ B,
    float* __restrict__ Cf, const float* __restrict__ bias0,
    short* __restrict__ qhi, short* __restrict__ qlo,
    short* __restrict__ khi, short* __restrict__ klo, short* __restrict__ vt,
    const float* __restrict__ biasq, const float* __restrict__ biask,
    const float* __restrict__ biasv)
{
    __shared__ short smem[16384];   // 32KB: As/Bs staging; reused as epilogue bounce
    int tid = threadIdx.x;
    int l = tid & 63, w = tid >> 6;
    int lr = l & 15, lg = l >> 4;
    int wm = w >> 1, wn = w & 1;
    int m0 = blockIdx.y * 128, n0 = blockIdx.x * 128;

    f32x4 acc[4][4] = {};

    int sr = l >> 2;
    int sc = (l & 3) * 16;
    const char* Ag = (const char*)A + ((size_t)(m0 + w * 32 + sr) * 1024) * 2 + sc;
    const char* Bg = (const char*)B + ((size_t)(n0 + w * 32 + sr) * 1024) * 2 + sc;

    auto stage = [&](int buf, int t) {
        int kb = t * 64;
        #pragma unroll
        for (int g = 0; g < 2; ++g) {
            gload16(Ag + (size_t)g * (16 * 2048) + kb,
                    (char*)&smem[buf * 4096 + (w * 32 + g * 16) * 32]);
            gload16(Bg + (size_t)g * (16 * 2048) + kb,
                    (char*)&smem[8192 + buf * 4096 + (w * 32 + g * 16) * 32]);
        }
    };

    stage(0, 0);
    __syncthreads();

    int cur = 0;
    for (int t = 0; t < 32; ++t) {
        if (t < 31) stage(cur ^ 1, t + 1);
        short8 a[4], b[4];
        #pragma unroll
        for (int i = 0; i < 4; ++i)
            a[i] = *(const short8*)&smem[cur * 4096 + (wm * 64 + i * 16 + lr) * 32 + lg * 8];
        #pragma unroll
        for (int j = 0; j < 4; ++j)
            b[j] = *(const short8*)&smem[8192 + cur * 4096 + (wn * 64 + j * 16 + lr) * 32 + lg * 8];
        #pragma unroll
        for (int i = 0; i < 4; ++i)
            #pragma unroll
            for (int j = 0; j < 4; ++j)
                acc[i][j] = MFMA_BF16(a[i], b[j], acc[i][j]);
        __syncthreads();
        cur ^= 1;
    }

    if (EPI == 0) {
        #pragma unroll
        for (int i = 0; i < 4; ++i) {
            int m_base = m0 + wm * 64 + i * 16 + lg * 4;
            #pragma unroll
            for (int j = 0; j < 4; ++j) {
                int n = n0 + wn * 64 + j * 16 + lr;
                float bv = bias0[n];
                #pragma unroll
                for (int r = 0; r < 4; ++r)
                    Cf[(size_t)(m_base + r) * 1024 + n] = acc[i][j][r] + bv;
            }
        }
    } else {
        int sel = n0 >> 10;
        int nb = n0 & 1023;
        if (sel == 2) {
            // V: transpose to vt[(b*16+h)*64+d][s], bounced through LDS [n][m] swizzled
            #pragma unroll
            for (int i = 0; i < 4; ++i) {
                int ml = wm * 64 + i * 16 + lg * 4;
                #pragma unroll
                for (int j = 0; j < 4; ++j) {
                    int nl = wn * 64 + j * 16 + lr;
                    float bvv = biasv[nb + nl];
                    short4v o;
                    #pragma unroll
                    for (int r = 0; r < 4; ++r) o[r] = f2bf(acc[i][j][r] + bvv);
                    *(short4v*)((char*)smem + nl * 256 + ((ml * 2) ^ ((nl & 7) << 4))) = o;
                }
            }
            __syncthreads();
            int b_ = m0 >> 10, s0 = m0 & 1023;
            #pragma unroll
            for (int it = 0; it < 8; ++it) {
                int idx = it * 256 + tid;
                int nrow = idx >> 4, c8 = idx & 15;
                short8 vv = *(const short8*)((char*)smem + nrow * 256 +
                                             ((c8 * 16) ^ ((nrow & 7) << 4)));
                int ng = nb + nrow;
                int h = ng >> 6, d = ng & 63;
                *(short8*)(vt + (size_t)((b_ * 16 + h) * 64 + d) * 1024 + s0 + c8 * 8) = vv;
            }
        } else {
            short* Chi = sel ? khi : qhi;
            short* Clo = sel ? klo : qlo;
            const float* bias = sel ? biask : biasq;
            float ps = sel ? 1.0f : 0.125f;
            #pragma unroll
            for (int hv = 0; hv < 2; ++hv) {
                __syncthreads();
                #pragma unroll
                for (int i = 0; i < 4; ++i) {
                    int ml = wm * 64 + i * 16 + lg * 4;
                    #pragma unroll
                    for (int j = 0; j < 4; ++j) {
                        int nl = wn * 64 + j * 16 + lr;
                        float bvv = bias[nb + nl];
                        #pragma unroll
                        for (int r = 0; r < 4; ++r) {
                            float v = (acc[i][j][r] + bvv) * ps;
                            short hh = f2bf(v);
                            short ss = hv ? f2bf(v - bf2f(hh)) : hh;
                            smem[(ml + r) * 128 + nl] = ss;
                        }
                    }
                }
                __syncthreads();
                short* dst = hv ? Clo : Chi;
                #pragma unroll
                for (int it = 0; it < 8; ++it) {
                    int idx = it * 256 + tid;
                    int row = idx >> 4, c8 = idx & 15;
                    short8 vv = *(const short8*)&smem[row * 128 + c8 * 8];
                    *(short8*)(dst + (size_t)(m0 + row) * 1024 + nb + c8 * 8) = vv;
                }
            }
        }
    }
}

// -------- fused scores+softmax+PV (r15 kernel + coalesced probs epilogue) --------
// Block: 32 q-rows x full 1024 k, z = blockIdx.y. Swapped mfma(K,Q): C[m=k][n=q].
// P bf16 -> LDS (swizzled); probs written as 4KB-contiguous wave bursts from LDS
// readback (regular stores, NOT nontemporal); then PV from LDS.
__global__ __launch_bounds__(256) void attn_fused_kernel(
    const short* __restrict__ Qhi, const short* __restrict__ Qlo,
    const short* __restrict__ Khi, const short* __restrict__ Klo,
    const float* __restrict__ mask, float* __restrict__ P,
    const short* __restrict__ vt, short* __restrict__ ctxb)
{
    // [0,65536): P_lds (phase3+); overlays K staging [0,32768) + Q staging [32768,40960)
    constexpr int P_O = 0, KHI_O = 0, KLO_O = 16384, QHI_O = 32768, QLO_O = 36864,
                  MADD_O = 65536, WRM_O = 69632, WRL_O = 70144;
    __shared__ __align__(16) char lds[70656];

    int tid = threadIdx.x;
    int l = tid & 63, w = tid >> 6;
    int c = l & 15, g = l >> 4;
    int z = blockIdx.y;
    int b = z >> 4, h = z & 15;
    int qb = blockIdx.x;

    // madd[k] = (1 - mask[b][k]) * -10000
    {
        const float4* mrow = (const float4*)(mask + b * 1024);
        float4 mm = mrow[tid];
        float4 md;
        md.x = (1.0f - mm.x) * -10000.0f;
        md.y = (1.0f - mm.y) * -10000.0f;
        md.z = (1.0f - mm.z) * -10000.0f;
        md.w = (1.0f - mm.w) * -10000.0f;
        *(float4*)(lds + MADD_O + tid * 16) = md;
    }

    // stage Q hi/lo: 32 rows x 128B, XOR-swizzled via pre-swizzled global source
    {
        int r_ = w * 8 + (l >> 3);
        int ul = (l & 7) ^ (r_ & 7);
        size_t gq = ((size_t)(b * 1024 + qb * 32 + r_)) * 1024 + h * 64 + ul * 8;
        gload16(Qhi + gq, lds + QHI_O + w * 1024);
        gload16(Qlo + gq, lds + QLO_O + w * 1024);
    }
    asm volatile("s_waitcnt vmcnt(0)" ::: "memory");
    __syncthreads();

    // Q fragments (B operand): row = qt*16 + c
    short8 bqh[2][2], bql[2][2];
    #pragma unroll
    for (int qt = 0; qt < 2; ++qt) {
        int row = qt * 16 + c;
        #pragma unroll
        for (int dt = 0; dt < 2; ++dt) {
            int u = (dt * 4 + g) ^ (row & 7);
            bqh[qt][dt] = *(const short8*)(lds + QHI_O + row * 128 + u * 16);
            bql[qt][dt] = *(const short8*)(lds + QLO_O + row * 128 + u * 16);
        }
    }

    f32x4 acc[8][2][2] = {};

    // ---- QK: cooperative barriered K staging, 8 chunks of 128 rows (FULL unroll) ----
    #pragma unroll
    for (int cc = 0; cc < 8; ++cc) {
        #pragma unroll
        for (int i = 0; i < 4; ++i) {
            int r_ = i * 32 + w * 8 + (l >> 3);
            int ul = (l & 7) ^ (r_ & 7);
            size_t gk = ((size_t)(b * 1024 + cc * 128 + r_)) * 1024 + h * 64 + ul * 8;
            gload16(Khi + gk, lds + KHI_O + i * 4096 + w * 1024);
            gload16(Klo + gk, lds + KLO_O + i * 4096 + w * 1024);
        }
        asm volatile("s_waitcnt vmcnt(0)" ::: "memory");
        __syncthreads();

        #pragma unroll
        for (int kt = 0; kt < 2; ++kt) {
            int row = w * 32 + kt * 16 + c;
            #pragma unroll
            for (int dt = 0; dt < 2; ++dt) {
                int u = (dt * 4 + g) ^ (row & 7);
                short8 ah = *(const short8*)(lds + KHI_O + row * 128 + u * 16);
                short8 al = *(const short8*)(lds + KLO_O + row * 128 + u * 16);
                #pragma unroll
                for (int qt = 0; qt < 2; ++qt) {
                    acc[cc][kt][qt] = MFMA_BF16(ah, bqh[qt][dt], acc[cc][kt][qt]);
                    acc[cc][kt][qt] = MFMA_BF16(ah, bql[qt][dt], acc[cc][kt][qt]);
                    acc[cc][kt][qt] = MFMA_BF16(al, bqh[qt][dt], acc[cc][kt][qt]);
                }
            }
        }
        __syncthreads();
    }

    // ---- softmax ----
    float mx[2] = {-3.0e38f, -3.0e38f};
    #pragma unroll
    for (int cc = 0; cc < 8; ++cc)
        #pragma unroll
        for (int kt = 0; kt < 2; ++kt) {
            f32x4 md = *(const f32x4*)(lds + MADD_O + (cc * 128 + w * 32 + kt * 16 + g * 4) * 4);
            #pragma unroll
            for (int qt = 0; qt < 2; ++qt) {
                f32x4 v = acc[cc][kt][qt] + md;
                acc[cc][kt][qt] = v;
                mx[qt] = fmaxf(mx[qt], fmaxf(fmaxf(v[0], v[1]), fmaxf(v[2], v[3])));
            }
        }
    #pragma unroll
    for (int qt = 0; qt < 2; ++qt) {
        mx[qt] = fmaxf(mx[qt], __shfl_xor(mx[qt], 16));
        mx[qt] = fmaxf(mx[qt], __shfl_xor(mx[qt], 32));
    }
    float* wrm = (float*)(lds + WRM_O);
    float* wrl = (float*)(lds + WRL_O);
    if (g == 0) { wrm[w * 32 + c] = mx[0]; wrm[w * 32 + 16 + c] = mx[1]; }
    __syncthreads();
    float mfin[2];
    mfin[0] = fmaxf(fmaxf(wrm[c], wrm[32 + c]), fmaxf(wrm[64 + c], wrm[96 + c]));
    mfin[1] = fmaxf(fmaxf(wrm[16 + c], wrm[48 + c]), fmaxf(wrm[80 + c], wrm[112 + c]));

    float sum[2] = {0.0f, 0.0f};
    #pragma unroll
    for (int cc = 0; cc < 8; ++cc)
        #pragma unroll
        for (int kt = 0; kt < 2; ++kt)
            #pragma unroll
            for (int qt = 0; qt < 2; ++qt) {
                f32x4 v = acc[cc][kt][qt];
                v[0] = exp2f((v[0] - mfin[qt]) * LOG2E);
                v[1] = exp2f((v[1] - mfin[qt]) * LOG2E);
                v[2] = exp2f((v[2] - mfin[qt]) * LOG2E);
                v[3] = exp2f((v[3] - mfin[qt]) * LOG2E);
                acc[cc][kt][qt] = v;
                sum[qt] += (v[0] + v[1]) + (v[2] + v[3]);
            }
    #pragma unroll
    for (int qt = 0; qt < 2; ++qt) {
        sum[qt] += __shfl_xor(sum[qt], 16);
        sum[qt] += __shfl_xor(sum[qt], 32);
    }
    if (g == 0) { wrl[w * 32 + c] = sum[0]; wrl[w * 32 + 16 + c] = sum[1]; }
    __syncthreads();   // all waves past last K/Q LDS read -> P may overlay
    float inv[2];
    inv[0] = 1.0f / ((wrl[c] + wrl[32 + c]) + (wrl[64 + c] + wrl[96 + c]));
    inv[1] = 1.0f / ((wrl[16 + c] + wrl[48 + c]) + (wrl[80 + c] + wrl[112 + c]));

    // ---- P (bf16, normalized) into LDS only, XOR-swizzled per row ----
    #pragma unroll
    for (int cc = 0; cc < 8; ++cc)
        #pragma unroll
        for (int kt = 0; kt < 2; ++kt)
            #pragma unroll
            for (int qt = 0; qt < 2; ++qt) {
                f32x4 v = acc[cc][kt][qt];
                v[0] *= inv[qt]; v[1] *= inv[qt]; v[2] *= inv[qt]; v[3] *= inv[qt];
                int q = qt * 16 + c;
                int k = cc * 128 + w * 32 + kt * 16 + g * 4;
                short4v ps4;
                ps4[0] = f2bf(v[0]); ps4[1] = f2bf(v[1]);
                ps4[2] = f2bf(v[2]); ps4[3] = f2bf(v[3]);
                *(short4v*)(lds + P_O + q * 2048 + ((k * 2) ^ ((q & 7) << 4))) = ps4;
            }
    __syncthreads();

    // ---- probs f32: coalesced 64B/lane regular stores from LDS readback ----
    // wave w owns rows w*8..w*8+7; each row = 4KB contiguous per wave instruction set
    {
        float* Pz = P + ((size_t)z << 20) + (size_t)(qb * 32) * 1024;
        #pragma unroll
        for (int rr = 0; rr < 8; ++rr) {
            int q = w * 8 + rr;
            int swz = (q & 7) << 4;
            int kb = l * 32;
            short8 s0 = *(const short8*)(lds + P_O + q * 2048 + (kb ^ swz));
            short8 s1 = *(const short8*)(lds + P_O + q * 2048 + ((kb + 16) ^ swz));
            float* dst = Pz + (size_t)q * 1024 + l * 16;
            f32x4 o;
            o[0] = bf2f(s0[0]); o[1] = bf2f(s0[1]); o[2] = bf2f(s0[2]); o[3] = bf2f(s0[3]);
            *(f32x4*)dst = o;
            o[0] = bf2f(s0[4]); o[1] = bf2f(s0[5]); o[2] = bf2f(s0[6]); o[3] = bf2f(s0[7]);
            *(f32x4*)(dst + 4) = o;
            o[0] = bf2f(s1[0]); o[1] = bf2f(s1[1]); o[2] = bf2f(s1[2]); o[3] = bf2f(s1[3]);
            *(f32x4*)(dst + 8) = o;
            o[0] = bf2f(s1[4]); o[1] = bf2f(s1[5]); o[2] = bf2f(s1[6]); o[3] = bf2f(s1[7]);
            *(f32x4*)(dst + 12) = o;
        }
    }

    // PV: ctx[32q][64d] = P @ V; wave w owns d = w*16 + c; V streamed from global (L2-hot)
    {
        const short* vbase = vt + (size_t)z * 65536 + (size_t)(w * 16 + c) * 1024 + g * 8;
        f32x4 pacc[2] = {};
        short8 vfrag = *(const short8*)vbase;
        for (int kc = 0; kc < 32; ++kc) {
            short8 vnext = {};
            if (kc < 31) vnext = *(const short8*)(vbase + (kc + 1) * 32);
            short8 pa[2];
            #pragma unroll
            for (int qt = 0; qt < 2; ++qt) {
                int q = qt * 16 + c;
                int kbyte = kc * 64 + g * 16;
                pa[qt] = *(const short8*)(lds + P_O + q * 2048 + (kbyte ^ ((q & 7) << 4)));
            }
            pacc[0] = MFMA_BF16(pa[0], vfrag, pacc[0]);
            pacc[1] = MFMA_BF16(pa[1], vfrag, pacc[1]);
            vfrag = vnext;
        }
        #pragma unroll
        for (int qt = 0; qt < 2; ++qt) {
            int s = qb * 32 + qt * 16 + g * 4;
            size_t base = ((size_t)b * 1024 + s) * 1024 + h * 64 + w * 16 + c;
            #pragma unroll
            for (int r = 0; r < 4; ++r)
                ctxb[base + (size_t)r * 1024] = f2bf(pacc[qt][r]);
        }
    }
}

extern "C" void kernel_launch(void* const* d_in, const int* in_sizes, int n_in,
                              void* d_out, int out_size, void* d_ws, size_t ws_size,
                              hipStream_t stream) {
    const float* hs   = (const float*)d_in[0];
    const float* mask = (const float*)d_in[1];
    const float* Wq   = (const float*)d_in[2];
    const float* bq   = (const float*)d_in[3];
    const float* Wk   = (const float*)d_in[4];
    const float* bk   = (const float*)d_in[5];
    const float* Wv   = (const float*)d_in[6];
    const float* bv   = (const float*)d_in[7];
    const float* Wo   = (const float*)d_in[8];
    const float* bo   = (const float*)d_in[9];

    float* out   = (float*)d_out;
    float* probs = out + 4194304;

    char* ws = (char*)d_ws;
    short* qhi  = (short*)(ws);
    short* qlo  = (short*)(ws + (8u << 20));
    short* khi  = (short*)(ws + (16u << 20));
    short* klo  = (short*)(ws + (24u << 20));
    short* vt   = (short*)(ws + (32u << 20));
    short* ctxb = (short*)(ws + (40u << 20));
    short* hsb  = (short*)(ws + (48u << 20));
    short* wcat = (short*)(ws + (56u << 20));   // Wq|Wk|Wv|Wo bf16
    short* wob  = wcat + 3 * (1u << 20);

    dim3 blk(256);

    // merged converts: hs (2048 blocks) + Wq/Wk/Wv/Wo (2048 blocks)
    cvt_all_kernel<<<4096, blk, 0, stream>>>(hs, hsb, Wq, Wk, Wv, Wo, wcat);

    // fused QKV projection: [4096][1024] @ [3072][1024]^T
    gemm128_kernel<1><<<dim3(24, 32), blk, 0, stream>>>(
        hsb, wcat, nullptr, nullptr, qhi, qlo, khi, klo, vt, bq, bk, bv);

    // fused scores+softmax+PV -> probs + ctx
    attn_fused_kernel<<<dim3(32, 64), blk, 0, stream>>>(qhi, qlo, khi, klo, mask, probs,
                                                        vt, ctxb);

    // out = ctx @ Wo^T + bo
    gemm128_kernel<0><<<dim3(8, 32), blk, 0, stream>>>(
        ctxb, wob, out, bo, nullptr, nullptr, nullptr, nullptr, nullptr,
        nullptr, nullptr, nullptr);
}

// Round 18
// 202.223 us; speedup vs baseline: 1.1593x; 1.1593x over previous
//
#include <hip/hip_runtime.h>
#include <hip/hip_bf16.h>

// MHA fwd: B=4, S=1024, H=1024, NH=16, HD=64. fp32 in/out, bf16 MFMA inside.
// d_out = [out 4096x1024 f32] ++ [probs 64x1024x1024 f32]
// d_ws (64MB): qhi 8M | qlo 8M | khi 8M | klo 8M | vt 8M | ctxb 8M | hsb 8M | Wcat 8M
//
// ROUND-17: r15 (208.0us best) + LDS diet 70656->46080 B (3 blocks/CU) via two-half
// P buffer. Clean retest of r11's idea (its bench was confounded by an acc scratch
// spill from `#pragma unroll 1`). Probs stores stay DIRECT from acc (r16 proved the
// LDS-readback epilogue costs +26us). All acc-indexed loops fully unrolled (rule #20).

typedef __attribute__((ext_vector_type(8))) short short8;
typedef __attribute__((ext_vector_type(4))) float f32x4;
typedef __attribute__((ext_vector_type(4))) short short4v;

#define LOG2E 1.44269504f
#define MFMA_BF16(a, b, c) __builtin_amdgcn_mfma_f32_16x16x32_bf16((a), (b), (c), 0, 0, 0)

__device__ __forceinline__ short f2bf(float x) {
    __hip_bfloat16 h = __float2bfloat16(x);
    return __builtin_bit_cast(short, h);
}
__device__ __forceinline__ float bf2f(short s) {
    unsigned int u = ((unsigned int)(unsigned short)s) << 16;
    return __builtin_bit_cast(float, u);
}

__device__ __forceinline__ void gload16(const void* g, void* lds) {
    __builtin_amdgcn_global_load_lds(
        (const __attribute__((address_space(1))) void*)g,
        (__attribute__((address_space(3))) void*)lds, 16, 0, 0);
}

// ---------------- fp32 -> bf16 convert, merged: hs (blocks 0..2047) + 4 weights ----------
__global__ __launch_bounds__(256) void cvt_all_kernel(
    const float* __restrict__ hs, short* __restrict__ hsb,
    const float* __restrict__ w0, const float* __restrict__ w1,
    const float* __restrict__ w2, const float* __restrict__ w3,
    short* __restrict__ wcat)
{
    int blk = blockIdx.x;
    const float* src;
    short* dst;
    int li;
    if (blk < 2048) {
        src = hs; dst = hsb;
        li = blk * 256 + threadIdx.x;
    } else {
        int sel = (blk - 2048) >> 9;
        const float* srcs[4] = {w0, w1, w2, w3};
        src = srcs[sel];
        dst = wcat + (size_t)sel * 1048576;
        li = ((blk - 2048) & 511) * 256 + threadIdx.x;
    }
    const float4* sp = (const float4*)src;
    float4 a = sp[li * 2], b = sp[li * 2 + 1];
    short8 o;
    o[0] = f2bf(a.x); o[1] = f2bf(a.y); o[2] = f2bf(a.z); o[3] = f2bf(a.w);
    o[4] = f2bf(b.x); o[5] = f2bf(b.y); o[6] = f2bf(b.z); o[7] = f2bf(b.w);
    *(short8*)(dst + (size_t)li * 8) = o;
}

// ---------------- 128x128-tile double-buffered NT GEMM, K=1024 ----------------
// EPI 0: Cf = A@B^T + bias (f32 row-major)
// EPI 1: QKV: n0<1024 -> Q hi/lo (*0.125); <2048 -> K hi/lo; else V->vt. LDS-bounce stores.
template <int EPI>
__global__ __launch_bounds__(256) void gemm128_kernel(
    const short* __restrict__ A, const short* __restrict__ B,
    float* __restrict__ Cf, const float* __restrict__ bias0,
    short* __restrict__ qhi, short* __restrict__ qlo,
    short* __restrict__ khi, short* __restrict__ klo, short* __restrict__ vt,
    const float* __restrict__ biasq, const float* __restrict__ biask,
    const float* __restrict__ biasv)
{
    __shared__ short smem[16384];   // 32KB: As/Bs staging; reused as epilogue bounce
    int tid = threadIdx.x;
    int l = tid & 63, w = tid >> 6;
    int lr = l & 15, lg = l >> 4;
    int wm = w >> 1, wn = w & 1;
    int m0 = blockIdx.y * 128, n0 = blockIdx.x * 128;

    f32x4 acc[4][4] = {};

    int sr = l >> 2;
    int sc = (l & 3) * 16;
    const char* Ag = (const char*)A + ((size_t)(m0 + w * 32 + sr) * 1024) * 2 + sc;
    const char* Bg = (const char*)B + ((size_t)(n0 + w * 32 + sr) * 1024) * 2 + sc;

    auto stage = [&](int buf, int t) {
        int kb = t * 64;
        #pragma unroll
        for (int g = 0; g < 2; ++g) {
            gload16(Ag + (size_t)g * (16 * 2048) + kb,
                    (char*)&smem[buf * 4096 + (w * 32 + g * 16) * 32]);
            gload16(Bg + (size_t)g * (16 * 2048) + kb,
                    (char*)&smem[8192 + buf * 4096 + (w * 32 + g * 16) * 32]);
        }
    };

    stage(0, 0);
    __syncthreads();

    int cur = 0;
    for (int t = 0; t < 32; ++t) {
        if (t < 31) stage(cur ^ 1, t + 1);
        short8 a[4], b[4];
        #pragma unroll
        for (int i = 0; i < 4; ++i)
            a[i] = *(const short8*)&smem[cur * 4096 + (wm * 64 + i * 16 + lr) * 32 + lg * 8];
        #pragma unroll
        for (int j = 0; j < 4; ++j)
            b[j] = *(const short8*)&smem[8192 + cur * 4096 + (wn * 64 + j * 16 + lr) * 32 + lg * 8];
        #pragma unroll
        for (int i = 0; i < 4; ++i)
            #pragma unroll
            for (int j = 0; j < 4; ++j)
                acc[i][j] = MFMA_BF16(a[i], b[j], acc[i][j]);
        __syncthreads();
        cur ^= 1;
    }

    if (EPI == 0) {
        #pragma unroll
        for (int i = 0; i < 4; ++i) {
            int m_base = m0 + wm * 64 + i * 16 + lg * 4;
            #pragma unroll
            for (int j = 0; j < 4; ++j) {
                int n = n0 + wn * 64 + j * 16 + lr;
                float bv = bias0[n];
                #pragma unroll
                for (int r = 0; r < 4; ++r)
                    Cf[(size_t)(m_base + r) * 1024 + n] = acc[i][j][r] + bv;
            }
        }
    } else {
        int sel = n0 >> 10;
        int nb = n0 & 1023;
        if (sel == 2) {
            // V: transpose to vt[(b*16+h)*64+d][s], bounced through LDS [n][m] swizzled
            #pragma unroll
            for (int i = 0; i < 4; ++i) {
                int ml = wm * 64 + i * 16 + lg * 4;
                #pragma unroll
                for (int j = 0; j < 4; ++j) {
                    int nl = wn * 64 + j * 16 + lr;
                    float bvv = biasv[nb + nl];
                    short4v o;
                    #pragma unroll
                    for (int r = 0; r < 4; ++r) o[r] = f2bf(acc[i][j][r] + bvv);
                    *(short4v*)((char*)smem + nl * 256 + ((ml * 2) ^ ((nl & 7) << 4))) = o;
                }
            }
            __syncthreads();
            int b_ = m0 >> 10, s0 = m0 & 1023;
            #pragma unroll
            for (int it = 0; it < 8; ++it) {
                int idx = it * 256 + tid;
                int nrow = idx >> 4, c8 = idx & 15;
                short8 vv = *(const short8*)((char*)smem + nrow * 256 +
                                             ((c8 * 16) ^ ((nrow & 7) << 4)));
                int ng = nb + nrow;
                int h = ng >> 6, d = ng & 63;
                *(short8*)(vt + (size_t)((b_ * 16 + h) * 64 + d) * 1024 + s0 + c8 * 8) = vv;
            }
        } else {
            short* Chi = sel ? khi : qhi;
            short* Clo = sel ? klo : qlo;
            const float* bias = sel ? biask : biasq;
            float ps = sel ? 1.0f : 0.125f;
            #pragma unroll
            for (int hv = 0; hv < 2; ++hv) {
                __syncthreads();
                #pragma unroll
                for (int i = 0; i < 4; ++i) {
                    int ml = wm * 64 + i * 16 + lg * 4;
                    #pragma unroll
                    for (int j = 0; j < 4; ++j) {
                        int nl = wn * 64 + j * 16 + lr;
                        float bvv = bias[nb + nl];
                        #pragma unroll
                        for (int r = 0; r < 4; ++r) {
                            float v = (acc[i][j][r] + bvv) * ps;
                            short hh = f2bf(v);
                            short ss = hv ? f2bf(v - bf2f(hh)) : hh;
                            smem[(ml + r) * 128 + nl] = ss;
                        }
                    }
                }
                __syncthreads();
                short* dst = hv ? Clo : Chi;
                #pragma unroll
                for (int it = 0; it < 8; ++it) {
                    int idx = it * 256 + tid;
                    int row = idx >> 4, c8 = idx & 15;
                    short8 vv = *(const short8*)&smem[row * 128 + c8 * 8];
                    *(short8*)(dst + (size_t)(m0 + row) * 1024 + nb + c8 * 8) = vv;
                }
            }
        }
    }
}

// -------- fused scores+softmax+PV (r15 structure, LDS 46080B -> 3 blocks/CU) --------
// Block: 32 q-rows x full 1024 k, z = blockIdx.y. Swapped mfma(K,Q): C[m=k][n=q].
// P written to LDS in two 32KB k-halves (overlay K staging after softmax barriers);
// probs stay DIRECT-from-acc scatter stores (proven fastest, r16).
__global__ __launch_bounds__(256) void attn_fused_kernel(
    const short* __restrict__ Qhi, const short* __restrict__ Qlo,
    const short* __restrict__ Khi, const short* __restrict__ Klo,
    const float* __restrict__ mask, float* __restrict__ P,
    const short* __restrict__ vt, short* __restrict__ ctxb)
{
    // KHI [0,16384), KLO [16384,32768), Q [32768,40960), madd [40960,45056),
    // wrm [45056,45568), wrl [45568,46080). P half [32 q][512 k] bf16 overlays [0,32768).
    constexpr int P_O = 0, KHI_O = 0, KLO_O = 16384, QHI_O = 32768, QLO_O = 36864,
                  MADD_O = 40960, WRM_O = 45056, WRL_O = 45568;
    __shared__ __align__(16) char lds[46080];

    int tid = threadIdx.x;
    int l = tid & 63, w = tid >> 6;
    int c = l & 15, g = l >> 4;
    int z = blockIdx.y;
    int b = z >> 4, h = z & 15;
    int qb = blockIdx.x;

    // madd[k] = (1 - mask[b][k]) * -10000
    {
        const float4* mrow = (const float4*)(mask + b * 1024);
        float4 mm = mrow[tid];
        float4 md;
        md.x = (1.0f - mm.x) * -10000.0f;
        md.y = (1.0f - mm.y) * -10000.0f;
        md.z = (1.0f - mm.z) * -10000.0f;
        md.w = (1.0f - mm.w) * -10000.0f;
        *(float4*)(lds + MADD_O + tid * 16) = md;
    }

    // stage Q hi/lo: 32 rows x 128B, XOR-swizzled via pre-swizzled global source
    {
        int r_ = w * 8 + (l >> 3);
        int ul = (l & 7) ^ (r_ & 7);
        size_t gq = ((size_t)(b * 1024 + qb * 32 + r_)) * 1024 + h * 64 + ul * 8;
        gload16(Qhi + gq, lds + QHI_O + w * 1024);
        gload16(Qlo + gq, lds + QLO_O + w * 1024);
    }
    asm volatile("s_waitcnt vmcnt(0)" ::: "memory");
    __syncthreads();

    // Q fragments (B operand): row = qt*16 + c
    short8 bqh[2][2], bql[2][2];
    #pragma unroll
    for (int qt = 0; qt < 2; ++qt) {
        int row = qt * 16 + c;
        #pragma unroll
        for (int dt = 0; dt < 2; ++dt) {
            int u = (dt * 4 + g) ^ (row & 7);
            bqh[qt][dt] = *(const short8*)(lds + QHI_O + row * 128 + u * 16);
            bql[qt][dt] = *(const short8*)(lds + QLO_O + row * 128 + u * 16);
        }
    }

    f32x4 acc[8][2][2] = {};

    // ---- QK: cooperative barriered K staging, 8 chunks of 128 rows (FULL unroll) ----
    #pragma unroll
    for (int cc = 0; cc < 8; ++cc) {
        #pragma unroll
        for (int i = 0; i < 4; ++i) {
            int r_ = i * 32 + w * 8 + (l >> 3);
            int ul = (l & 7) ^ (r_ & 7);
            size_t gk = ((size_t)(b * 1024 + cc * 128 + r_)) * 1024 + h * 64 + ul * 8;
            gload16(Khi + gk, lds + KHI_O + i * 4096 + w * 1024);
            gload16(Klo + gk, lds + KLO_O + i * 4096 + w * 1024);
        }
        asm volatile("s_waitcnt vmcnt(0)" ::: "memory");
        __syncthreads();

        #pragma unroll
        for (int kt = 0; kt < 2; ++kt) {
            int row = w * 32 + kt * 16 + c;
            #pragma unroll
            for (int dt = 0; dt < 2; ++dt) {
                int u = (dt * 4 + g) ^ (row & 7);
                short8 ah = *(const short8*)(lds + KHI_O + row * 128 + u * 16);
                short8 al = *(const short8*)(lds + KLO_O + row * 128 + u * 16);
                #pragma unroll
                for (int qt = 0; qt < 2; ++qt) {
                    acc[cc][kt][qt] = MFMA_BF16(ah, bqh[qt][dt], acc[cc][kt][qt]);
                    acc[cc][kt][qt] = MFMA_BF16(ah, bql[qt][dt], acc[cc][kt][qt]);
                    acc[cc][kt][qt] = MFMA_BF16(al, bqh[qt][dt], acc[cc][kt][qt]);
                }
            }
        }
        __syncthreads();
    }

    // ---- softmax ----
    float mx[2] = {-3.0e38f, -3.0e38f};
    #pragma unroll
    for (int cc = 0; cc < 8; ++cc)
        #pragma unroll
        for (int kt = 0; kt < 2; ++kt) {
            f32x4 md = *(const f32x4*)(lds + MADD_O + (cc * 128 + w * 32 + kt * 16 + g * 4) * 4);
            #pragma unroll
            for (int qt = 0; qt < 2; ++qt) {
                f32x4 v = acc[cc][kt][qt] + md;
                acc[cc][kt][qt] = v;
                mx[qt] = fmaxf(mx[qt], fmaxf(fmaxf(v[0], v[1]), fmaxf(v[2], v[3])));
            }
        }
    #pragma unroll
    for (int qt = 0; qt < 2; ++qt) {
        mx[qt] = fmaxf(mx[qt], __shfl_xor(mx[qt], 16));
        mx[qt] = fmaxf(mx[qt], __shfl_xor(mx[qt], 32));
    }
    float* wrm = (float*)(lds + WRM_O);
    float* wrl = (float*)(lds + WRL_O);
    if (g == 0) { wrm[w * 32 + c] = mx[0]; wrm[w * 32 + 16 + c] = mx[1]; }
    __syncthreads();
    float mfin[2];
    mfin[0] = fmaxf(fmaxf(wrm[c], wrm[32 + c]), fmaxf(wrm[64 + c], wrm[96 + c]));
    mfin[1] = fmaxf(fmaxf(wrm[16 + c], wrm[48 + c]), fmaxf(wrm[80 + c], wrm[112 + c]));

    float sum[2] = {0.0f, 0.0f};
    #pragma unroll
    for (int cc = 0; cc < 8; ++cc)
        #pragma unroll
        for (int kt = 0; kt < 2; ++kt)
            #pragma unroll
            for (int qt = 0; qt < 2; ++qt) {
                f32x4 v = acc[cc][kt][qt];
                v[0] = exp2f((v[0] - mfin[qt]) * LOG2E);
                v[1] = exp2f((v[1] - mfin[qt]) * LOG2E);
                v[2] = exp2f((v[2] - mfin[qt]) * LOG2E);
                v[3] = exp2f((v[3] - mfin[qt]) * LOG2E);
                acc[cc][kt][qt] = v;
                sum[qt] += (v[0] + v[1]) + (v[2] + v[3]);
            }
    #pragma unroll
    for (int qt = 0; qt < 2; ++qt) {
        sum[qt] += __shfl_xor(sum[qt], 16);
        sum[qt] += __shfl_xor(sum[qt], 32);
    }
    if (g == 0) { wrl[w * 32 + c] = sum[0]; wrl[w * 32 + 16 + c] = sum[1]; }
    __syncthreads();   // all waves past last K/Q LDS read -> P half may overlay
    float inv[2];
    inv[0] = 1.0f / ((wrl[c] + wrl[32 + c]) + (wrl[64 + c] + wrl[96 + c]));
    inv[1] = 1.0f / ((wrl[16 + c] + wrl[48 + c]) + (wrl[80 + c] + wrl[112 + c]));

    // ---- probs (direct scatter, proven) + PV in two k-halves ----
    float* Pz = P + ((size_t)z << 20);
    const short* vbase = vt + (size_t)z * 65536 + (size_t)(w * 16 + c) * 1024 + g * 8;
    f32x4 pacc[2] = {};

    #pragma unroll
    for (int h2 = 0; h2 < 2; ++h2) {
        // write probs f32 global (direct from acc) + bf16 P into LDS half (swizzled)
        #pragma unroll
        for (int cc2 = 0; cc2 < 4; ++cc2) {
            int cc = h2 * 4 + cc2;
            #pragma unroll
            for (int kt = 0; kt < 2; ++kt)
                #pragma unroll
                for (int qt = 0; qt < 2; ++qt) {
                    f32x4 v = acc[cc][kt][qt];
                    v[0] *= inv[qt]; v[1] *= inv[qt]; v[2] *= inv[qt]; v[3] *= inv[qt];
                    int q = qt * 16 + c;
                    int k = cc * 128 + w * 32 + kt * 16 + g * 4;   // global k
                    *(f32x4*)(Pz + (size_t)(qb * 32 + q) * 1024 + k) = v;
                    int kl = k - h2 * 512;                          // 0..511 within half
                    short4v ps4;
                    ps4[0] = f2bf(v[0]); ps4[1] = f2bf(v[1]);
                    ps4[2] = f2bf(v[2]); ps4[3] = f2bf(v[3]);
                    *(short4v*)(lds + P_O + q * 1024 + ((kl * 2) ^ ((q & 7) << 4))) = ps4;
                }
        }
        __syncthreads();

        // PV over this half: 16 chunks of 32 k
        #pragma unroll
        for (int kc = 0; kc < 16; ++kc) {
            short8 vfrag = *(const short8*)(vbase + h2 * 512 + kc * 32);
            short8 pa[2];
            #pragma unroll
            for (int qt = 0; qt < 2; ++qt) {
                int q = qt * 16 + c;
                int kbyte = kc * 64 + g * 16;
                pa[qt] = *(const short8*)(lds + P_O + q * 1024 + (kbyte ^ ((q & 7) << 4)));
            }
            pacc[0] = MFMA_BF16(pa[0], vfrag, pacc[0]);
            pacc[1] = MFMA_BF16(pa[1], vfrag, pacc[1]);
        }
        __syncthreads();   // before next half overwrites P
    }

    // ctx[32q][64d]: wave w owns d = w*16 + c
    #pragma unroll
    for (int qt = 0; qt < 2; ++qt) {
        int s = qb * 32 + qt * 16 + g * 4;
        size_t base = ((size_t)b * 1024 + s) * 1024 + h * 64 + w * 16 + c;
        #pragma unroll
        for (int r = 0; r < 4; ++r)
            ctxb[base + (size_t)r * 1024] = f2bf(pacc[qt][r]);
    }
}

extern "C" void kernel_launch(void* const* d_in, const int* in_sizes, int n_in,
                              void* d_out, int out_size, void* d_ws, size_t ws_size,
                              hipStream_t stream) {
    const float* hs   = (const float*)d_in[0];
    const float* mask = (const float*)d_in[1];
    const float* Wq   = (const float*)d_in[2];
    const float* bq   = (const float*)d_in[3];
    const float* Wk   = (const float*)d_in[4];
    const float* bk   = (const float*)d_in[5];
    const float* Wv   = (const float*)d_in[6];
    const float* bv   = (const float*)d_in[7];
    const float* Wo   = (const float*)d_in[8];
    const float* bo   = (const float*)d_in[9];

    float* out   = (float*)d_out;
    float* probs = out + 4194304;

    char* ws = (char*)d_ws;
    short* qhi  = (short*)(ws);
    short* qlo  = (short*)(ws + (8u << 20));
    short* khi  = (short*)(ws + (16u << 20));
    short* klo  = (short*)(ws + (24u << 20));
    short* vt   = (short*)(ws + (32u << 20));
    short* ctxb = (short*)(ws + (40u << 20));
    short* hsb  = (short*)(ws + (48u << 20));
    short* wcat = (short*)(ws + (56u << 20));   // Wq|Wk|Wv|Wo bf16
    short* wob  = wcat + 3 * (1u << 20);

    dim3 blk(256);

    cvt_all_kernel<<<4096, blk, 0, stream>>>(hs, hsb, Wq, Wk, Wv, Wo, wcat);

    // fused QKV projection: [4096][1024] @ [3072][1024]^T
    gemm128_kernel<1><<<dim3(24, 32), blk, 0, stream>>>(
        hsb, wcat, nullptr, nullptr, qhi, qlo, khi, klo, vt, bq, bk, bv);

    // fused scores+softmax+PV -> probs + ctx
    attn_fused_kernel<<<dim3(32, 64), blk, 0, stream>>>(qhi, qlo, khi, klo, mask, probs,
                                                        vt, ctxb);

    // out = ctx @ Wo^T + bo
    gemm128_kernel<0><<<dim3(8, 32), blk, 0, stream>>>(
        ctxb, wob, out, bo, nullptr, nullptr, nullptr, nullptr, nullptr,
        nullptr, nullptr, nullptr);
}